// Round 11
// baseline (53.112 us; speedup 1.0000x reference)
//
#include <hip/hip_runtime.h>
#include <hip/hip_bf16.h>
#include <stdint.h>

typedef int v4i __attribute__((ext_vector_type(4)));

#define M_TOK 2048
#define NFEAT 2048
#define KDIM  2048

// ---------- fused absmax+quant: slice lives in registers, one HBM read ----------
// 512 blocks (b<256 -> x, else w), 16 float4/thread = 64 VGPR data slice.
// pmax[512] zeroed by a tiny memset node; partials stored release/agent;
// ONLY wave 0 spins (relaxed agent loads + s_sleep backoff) -> no R8 storm.
__global__ __launch_bounds__(256) void k_maxquant(const float4* __restrict__ x,
                                                  const float4* __restrict__ w,
                                                  char4* __restrict__ qx,
                                                  char4* __restrict__ qw,
                                                  float* __restrict__ pmax) {
  const int bid = blockIdx.x, tid = threadIdx.x;
  const int which = bid >> 8, sub = bid & 255;
  const float4* __restrict__ src = which ? w : x;
  char4* __restrict__ dst = which ? qw : qx;
  const int wid = tid >> 6, lane = tid & 63;
  __shared__ float sm[4];

  // phase A: load own slice into registers, partial absmax
  float4 v[16];
  float m = 0.0f;
  #pragma unroll
  for (int j = 0; j < 16; ++j) {
    v[j] = src[sub * 256 + tid + j * 65536];
    m = fmaxf(m, fmaxf(fmaxf(fabsf(v[j].x), fabsf(v[j].y)),
                       fmaxf(fabsf(v[j].z), fabsf(v[j].w))));
  }
  #pragma unroll
  for (int o = 32; o; o >>= 1) m = fmaxf(m, __shfl_down(m, o, 64));
  if (lane == 0) sm[wid] = m;
  __syncthreads();
  if (tid == 0) {
    const float bm = fmaxf(fmaxf(sm[0], sm[1]), fmaxf(sm[2], sm[3]));
    __hip_atomic_store(&pmax[bid], bm, __ATOMIC_RELEASE, __HIP_MEMORY_SCOPE_AGENT);
  }

  // wave 0 spins until all 256 partials of OWN half are positive
  if (wid == 0) {
    const int base = which * 256 + lane * 4;
    for (;;) {
      float a0 = __hip_atomic_load(&pmax[base + 0], __ATOMIC_RELAXED, __HIP_MEMORY_SCOPE_AGENT);
      float a1 = __hip_atomic_load(&pmax[base + 1], __ATOMIC_RELAXED, __HIP_MEMORY_SCOPE_AGENT);
      float a2 = __hip_atomic_load(&pmax[base + 2], __ATOMIC_RELAXED, __HIP_MEMORY_SCOPE_AGENT);
      float a3 = __hip_atomic_load(&pmax[base + 3], __ATOMIC_RELAXED, __HIP_MEMORY_SCOPE_AGENT);
      if (__all(fminf(fminf(a0, a1), fminf(a2, a3)) > 0.0f)) break;
      __builtin_amdgcn_s_sleep(8);
    }
  }
  __syncthreads();

  // all threads: reduce own half's 256 partials -> global max
  float g = __hip_atomic_load(&pmax[which * 256 + tid], __ATOMIC_RELAXED,
                              __HIP_MEMORY_SCOPE_AGENT);
  #pragma unroll
  for (int o = 32; o; o >>= 1) g = fmaxf(g, __shfl_down(g, o, 64));
  if (lane == 0) sm[wid] = g;
  __syncthreads();
  const float gmax = fmaxf(fmaxf(sm[0], sm[1]), fmaxf(sm[2], sm[3]));
  const float s = gmax / 127.0f;         // IEEE div, matches np

  // quantize straight from registers (no second read)
  #pragma unroll
  for (int j = 0; j < 16; ++j) {
    char4 q;
    q.x = (signed char)(int)fminf(127.f, fmaxf(-127.f, rintf(v[j].x / s)));
    q.y = (signed char)(int)fminf(127.f, fmaxf(-127.f, rintf(v[j].y / s)));
    q.z = (signed char)(int)fminf(127.f, fmaxf(-127.f, rintf(v[j].z / s)));
    q.w = (signed char)(int)fminf(127.f, fmaxf(-127.f, rintf(v[j].w / s)));
    dst[sub * 256 + tid + j * 65536] = q;
  }
}

// ---------- int8 GEMM: 128x128 tile, BK=64, 8 waves (2x4) of 64x32 ----------
__device__ __forceinline__ void gload16(const void* g, void* l) {
  __builtin_amdgcn_global_load_lds(
      (const __attribute__((address_space(1))) uint32_t*)(uintptr_t)g,
      (__attribute__((address_space(3))) uint32_t*)(uint32_t)(uintptr_t)l,
      16, 0, 0);
}

__global__ __launch_bounds__(512, 2) void k_gemm(const signed char* __restrict__ qa,
                                                 const signed char* __restrict__ qb,
                                                 const float* __restrict__ bias,
                                                 const float* __restrict__ pmax,
                                                 float* __restrict__ out) {
  __shared__ __align__(16) signed char ldsA[3][128 * 64];  // 24 KB
  __shared__ __align__(16) signed char ldsB[3][128 * 64];  // 24 KB
  __shared__ float smx[8], smw[8];
  const int tid = threadIdx.x;
  const int lane = tid & 63, wid = tid >> 6;   // 8 waves

  // XCD-aware bijective swizzle (36.2us config): 32 consecutive tiles per XCD
  const int bid = (blockIdx.x & 7) * 32 + (blockIdx.x >> 3);
  const int tm = (bid >> 4) * 128;
  const int tn = (bid & 15) * 128;

  const int wm = (wid >> 2) * 64;    // 2 wave-rows
  const int wn = (wid & 3) * 32;     // 4 wave-cols
  const int kg = lane >> 4, lr = lane & 15;
  const int swz = (kg ^ (lr >> 2)) * 16;  // kchunk XOR swizzle byte offset

  v4i acc[4][2] = {};

  // stage tile kt: 512 chunks of 16B; chunk c=tid -> row=c>>2, kc=(c&3)^((c>>4)&3)
  auto stage = [&](int buf, int kt) {
    const int k0 = kt * 64;
    const int c = tid;
    const int row = c >> 2, kc = (c & 3) ^ ((c >> 4) & 3);
    const int ldsoff = (wid * 64) * 16;  // wave-uniform; HW adds lane*16
    gload16(qa + (size_t)(tm + row) * KDIM + k0 + kc * 16, &ldsA[buf][ldsoff]);
    gload16(qb + (size_t)(tn + row) * KDIM + k0 + kc * 16, &ldsB[buf][ldsoff]);
  };

  stage(0, 0);
  stage(1, 1);

  const int NKT = KDIM / 64;
  for (int kt = 0; kt < NKT; ++kt) {
    if (kt + 1 < NKT) asm volatile("s_waitcnt vmcnt(2)" ::: "memory");
    else              asm volatile("s_waitcnt vmcnt(0)" ::: "memory");
    __builtin_amdgcn_sched_barrier(0);
    __builtin_amdgcn_s_barrier();
    __builtin_amdgcn_sched_barrier(0);
    if (kt + 2 < NKT) stage((kt + 2) % 3, kt + 2);
    const int cur = kt % 3;
    v4i af[4], bf[2];
    #pragma unroll
    for (int mi = 0; mi < 4; ++mi)
      af[mi] = *(const v4i*)&ldsA[cur][(wm + mi * 16 + lr) * 64 + swz];
    #pragma unroll
    for (int ni = 0; ni < 2; ++ni)
      bf[ni] = *(const v4i*)&ldsB[cur][(wn + ni * 16 + lr) * 64 + swz];
    #pragma unroll
    for (int mi = 0; mi < 4; ++mi)
      #pragma unroll
      for (int ni = 0; ni < 2; ++ni)
        acc[mi][ni] = __builtin_amdgcn_mfma_i32_16x16x64_i8(af[mi], bf[ni], acc[mi][ni], 0, 0, 0);
  }

  // scales needed only in the epilogue (512 threads: index with tid&255)
  {
    float a = pmax[tid & 255], b = pmax[256 + (tid & 255)];
    #pragma unroll
    for (int o = 32; o; o >>= 1) {
      a = fmaxf(a, __shfl_down(a, o, 64));
      b = fmaxf(b, __shfl_down(b, o, 64));
    }
    if (lane == 0) { smx[wid] = a; smw[wid] = b; }
  }
  __syncthreads();
  float gx = smx[0], gw = smw[0];
  #pragma unroll
  for (int j = 1; j < 8; ++j) { gx = fmaxf(gx, smx[j]); gw = fmaxf(gw, smw[j]); }
  const float deq = (gx / 127.0f) * (gw / 127.0f);

  #pragma unroll
  for (int ni = 0; ni < 2; ++ni) {
    const int col = tn + wn + ni * 16 + lr;
    const float bv = bias[col];
    #pragma unroll
    for (int mi = 0; mi < 4; ++mi) {
      const int row0 = tm + wm + mi * 16 + kg * 4;
      #pragma unroll
      for (int r = 0; r < 4; ++r)
        out[(size_t)(row0 + r) * NFEAT + col] = (float)acc[mi][ni][r] * deq + bv;
    }
  }
}

extern "C" void kernel_launch(void* const* d_in, const int* in_sizes, int n_in,
                              void* d_out, int out_size, void* d_ws, size_t ws_size,
                              hipStream_t stream) {
  const float* x    = (const float*)d_in[0];
  const float* w    = (const float*)d_in[1];
  const float* bias = (const float*)d_in[2];
  float* out = (float*)d_out;

  float* pmax = (float*)d_ws;                        // 512 floats
  signed char* qx = (signed char*)d_ws + 8192;
  signed char* qw = qx + (size_t)M_TOK * KDIM;

  hipMemsetAsync(pmax, 0, 512 * sizeof(float), stream);  // spin-safe on first call
  k_maxquant<<<dim3(512), 256, 0, stream>>>((const float4*)x, (const float4*)w,
                                            (char4*)qx, (char4*)qw, pmax);
  k_gemm<<<dim3(256), 512, 0, stream>>>(qx, qw, bias, pmax, out);
}

// Round 12
// 34.931 us; speedup vs baseline: 1.5205x; 1.5205x over previous
//
#include <hip/hip_runtime.h>
#include <hip/hip_bf16.h>
#include <stdint.h>

typedef int v4i __attribute__((ext_vector_type(4)));

#define M_TOK 2048
#define NFEAT 2048
#define KDIM  2048

// ---------- absmax: 512 blocks; b<256 -> x, else w; plain stores to pmax ----------
__global__ __launch_bounds__(256) void k_absmax(const float4* __restrict__ x,
                                                const float4* __restrict__ w,
                                                float* __restrict__ pmax) {
  const int bid = blockIdx.x, tid = threadIdx.x;
  const int which = bid >> 8;            // 0: x, 1: w
  const int sub = bid & 255;
  const float4* src = which ? w : x;
  const int n4 = (M_TOK * KDIM) / 4;
  float m = 0.0f;
  for (int i = sub * 256 + tid; i < n4; i += 256 * 256) {
    float4 v = src[i];
    m = fmaxf(m, fmaxf(fmaxf(fabsf(v.x), fabsf(v.y)), fmaxf(fabsf(v.z), fabsf(v.w))));
  }
  #pragma unroll
  for (int o = 32; o; o >>= 1) m = fmaxf(m, __shfl_down(m, o, 64));
  __shared__ float sm[4];
  const int wid = tid >> 6, lane = tid & 63;
  if (lane == 0) sm[wid] = m;
  __syncthreads();
  if (tid == 0) pmax[bid] = fmaxf(fmaxf(sm[0], sm[1]), fmaxf(sm[2], sm[3]));
}

// ---------- quantize: 2048 blocks (b>>10 selects tensor), 4 float4/thread ----------
__global__ __launch_bounds__(256) void k_quant(const float4* __restrict__ x,
                                               const float4* __restrict__ w,
                                               char4* __restrict__ qx,
                                               char4* __restrict__ qw,
                                               const float* __restrict__ pmax) {
  const int bid = blockIdx.x, tid = threadIdx.x;
  const int which = bid >> 10;           // 0: x, 1: w
  const int sub = bid & 1023;
  const float4* src = which ? w : x;
  char4* dst = which ? qw : qx;
  __shared__ float sm[4];
  {
    const int wid = tid >> 6, lane = tid & 63;
    float m = pmax[which * 256 + tid];
    #pragma unroll
    for (int o = 32; o; o >>= 1) m = fmaxf(m, __shfl_down(m, o, 64));
    if (lane == 0) sm[wid] = m;
  }
  __syncthreads();
  const float gmax = fmaxf(fmaxf(sm[0], sm[1]), fmaxf(sm[2], sm[3]));
  const float s = gmax / 127.0f;         // IEEE div, matches np
  const int n4 = (M_TOK * KDIM) / 4;
  for (int i = sub * 256 + tid; i < n4; i += 1024 * 256) {
    float4 v = src[i];
    char4 q;
    q.x = (signed char)(int)fminf(127.f, fmaxf(-127.f, rintf(v.x / s)));
    q.y = (signed char)(int)fminf(127.f, fmaxf(-127.f, rintf(v.y / s)));
    q.z = (signed char)(int)fminf(127.f, fmaxf(-127.f, rintf(v.z / s)));
    q.w = (signed char)(int)fminf(127.f, fmaxf(-127.f, rintf(v.w / s)));
    dst[i] = q;
  }
}

// ---------- int8 GEMM: 128x128 tile, BK=64, 8 waves (2x4) of 64x32 ----------
__device__ __forceinline__ void gload16(const void* g, void* l) {
  __builtin_amdgcn_global_load_lds(
      (const __attribute__((address_space(1))) uint32_t*)(uintptr_t)g,
      (__attribute__((address_space(3))) uint32_t*)(uint32_t)(uintptr_t)l,
      16, 0, 0);
}

__global__ __launch_bounds__(512, 2) void k_gemm(const signed char* __restrict__ qa,
                                                 const signed char* __restrict__ qb,
                                                 const float* __restrict__ bias,
                                                 const float* __restrict__ pmax,
                                                 float* __restrict__ out) {
  __shared__ __align__(16) signed char ldsA[3][128 * 64];  // 24 KB
  __shared__ __align__(16) signed char ldsB[3][128 * 64];  // 24 KB
  __shared__ float smx[8], smw[8];
  const int tid = threadIdx.x;
  const int lane = tid & 63, wid = tid >> 6;   // 8 waves

  // XCD-aware bijective swizzle: 32 consecutive tiles per XCD
  const int bid = (blockIdx.x & 7) * 32 + (blockIdx.x >> 3);
  const int tm = (bid >> 4) * 128;
  const int tn = (bid & 15) * 128;

  const int wm = (wid >> 2) * 64;    // 2 wave-rows
  const int wn = (wid & 3) * 32;     // 4 wave-cols
  const int kg = lane >> 4, lr = lane & 15;
  const int swz = (kg ^ (lr >> 2)) * 16;  // kchunk XOR swizzle byte offset

  v4i acc[4][2] = {};

  // stage tile kt: 512 chunks of 16B; chunk c=tid -> row=c>>2, kc=(c&3)^((c>>4)&3)
  auto stage = [&](int buf, int kt) {
    const int k0 = kt * 64;
    const int c = tid;
    const int row = c >> 2, kc = (c & 3) ^ ((c >> 4) & 3);
    const int ldsoff = (wid * 64) * 16;  // wave-uniform; HW adds lane*16
    gload16(qa + (size_t)(tm + row) * KDIM + k0 + kc * 16, &ldsA[buf][ldsoff]);
    gload16(qb + (size_t)(tn + row) * KDIM + k0 + kc * 16, &ldsB[buf][ldsoff]);
  };

  stage(0, 0);
  stage(1, 1);

  const int NKT = KDIM / 64;
  for (int kt = 0; kt < NKT; ++kt) {
    if (kt + 1 < NKT) asm volatile("s_waitcnt vmcnt(2)" ::: "memory");
    else              asm volatile("s_waitcnt vmcnt(0)" ::: "memory");
    __builtin_amdgcn_sched_barrier(0);
    __builtin_amdgcn_s_barrier();
    __builtin_amdgcn_sched_barrier(0);
    if (kt + 2 < NKT) stage((kt + 2) % 3, kt + 2);
    const int cur = kt % 3;
    v4i af[4], bf[2];
    #pragma unroll
    for (int mi = 0; mi < 4; ++mi)
      af[mi] = *(const v4i*)&ldsA[cur][(wm + mi * 16 + lr) * 64 + swz];
    #pragma unroll
    for (int ni = 0; ni < 2; ++ni)
      bf[ni] = *(const v4i*)&ldsB[cur][(wn + ni * 16 + lr) * 64 + swz];
    #pragma unroll
    for (int mi = 0; mi < 4; ++mi)
      #pragma unroll
      for (int ni = 0; ni < 2; ++ni)
        acc[mi][ni] = __builtin_amdgcn_mfma_i32_16x16x64_i8(af[mi], bf[ni], acc[mi][ni], 0, 0, 0);
  }

  // scales needed only in the epilogue (512 threads: index with tid&255)
  {
    float a = pmax[tid & 255], b = pmax[256 + (tid & 255)];
    #pragma unroll
    for (int o = 32; o; o >>= 1) {
      a = fmaxf(a, __shfl_down(a, o, 64));
      b = fmaxf(b, __shfl_down(b, o, 64));
    }
    if (lane == 0) { smx[wid] = a; smw[wid] = b; }
  }
  __syncthreads();
  float gx = smx[0], gw = smw[0];
  #pragma unroll
  for (int j = 1; j < 8; ++j) { gx = fmaxf(gx, smx[j]); gw = fmaxf(gw, smw[j]); }
  const float deq = (gx / 127.0f) * (gw / 127.0f);

  #pragma unroll
  for (int ni = 0; ni < 2; ++ni) {
    const int col = tn + wn + ni * 16 + lr;
    const float bv = bias[col];
    #pragma unroll
    for (int mi = 0; mi < 4; ++mi) {
      const int row0 = tm + wm + mi * 16 + kg * 4;
      #pragma unroll
      for (int r = 0; r < 4; ++r)
        out[(size_t)(row0 + r) * NFEAT + col] = (float)acc[mi][ni][r] * deq + bv;
    }
  }
}

extern "C" void kernel_launch(void* const* d_in, const int* in_sizes, int n_in,
                              void* d_out, int out_size, void* d_ws, size_t ws_size,
                              hipStream_t stream) {
  const float* x    = (const float*)d_in[0];
  const float* w    = (const float*)d_in[1];
  const float* bias = (const float*)d_in[2];
  float* out = (float*)d_out;

  float* pmax = (float*)d_ws;                        // 512 floats
  signed char* qx = (signed char*)d_ws + 8192;
  signed char* qw = qx + (size_t)M_TOK * KDIM;

  k_absmax<<<dim3(512), 256, 0, stream>>>((const float4*)x, (const float4*)w, pmax);
  k_quant<<<dim3(2048), 256, 0, stream>>>(
      (const float4*)x, (const float4*)w, (char4*)qx, (char4*)qw, pmax);
  k_gemm<<<dim3(256), 512, 0, stream>>>(qx, qw, bias, pmax, out);
}